// Round 11
// baseline (2575.559 us; speedup 1.0000x reference)
//
#include <hip/hip_runtime.h>
#include <hip/hip_bf16.h>

#define B_   64
#define T_   2048
#define H_   128
#define G_   384      // 3*H
#define D0_  18
#define WIN  4
#define RING 8
#define NW   (T_ / WIN)   // 512

typedef __hip_bfloat16 bf16;
typedef __attribute__((ext_vector_type(4))) float f32x4;
typedef __attribute__((ext_vector_type(8))) short s16x8;

#define LOG2E  1.4426950408889634f
#define NEGL2E (-1.4426950408889634f)
#define TWOL2E (2.8853900817779268f)

// Exp2-domain gate math (weights pre-scaled: R,Z by -LOG2E; N by +2*LOG2E):
//   h' = n + z*(h-n) = [Ez*(En-1) + h*(En+1)] / [(En+1)*(1+Ez)]
__device__ __forceinline__ short f2bs(float v) {
    bf16 b = __float2bfloat16(v);
    return *reinterpret_cast<short*>(&b);
}
__device__ __forceinline__ unsigned short f2bu(float v) {
    bf16 b = __float2bfloat16(v);
    return *reinterpret_cast<unsigned short*>(&b);
}
// Pack 4 f32 -> uint2 of 4 bf16 (RNE) in 2 instrs.
__device__ __forceinline__ uint2 pk_bf16x4(float a, float b, float c, float d) {
    uint2 r;
    asm("v_cvt_pk_bf16_f32 %0, %1, %2" : "=v"(r.x) : "v"(a), "v"(b));
    asm("v_cvt_pk_bf16_f32 %0, %1, %2" : "=v"(r.y) : "v"(c), "v"(d));
    return r;
}
#define MFMA16(A, B, C) __builtin_amdgcn_mfma_f32_16x16x32_bf16((A), (B), (C), 0, 0, 0)

// Per-step sync: hardware barrier; vmcnt NOT drained (prefetch stays in flight).
__device__ __forceinline__ void step_sync() {
    __asm__ volatile("s_waitcnt lgkmcnt(0)" ::: "memory");
    __builtin_amdgcn_s_barrier();
    __asm__ volatile("" ::: "memory");
}

// Combined GRU update from exp2-domain accumulators. 8 regular + 5 trans ops.
__device__ __forceinline__ float gru_update(float yr, float yz, float aN,
                                            float aX, float h) {
    const float Er = __builtin_amdgcn_exp2f(yr);
    const float rg = __builtin_amdgcn_rcpf(1.0f + Er);
    const float En = __builtin_amdgcn_exp2f(fmaf(rg, aN, aX));
    const float Ez = __builtin_amdgcn_exp2f(yz);
    const float p  = fmaf(En, Ez, -Ez);        // Ez*(En-1), fma-exact
    const float q2 = fmaf(h, En, h);           // h*(En+1)
    const float t1 = Ez + 1.0f;
    const float dn = fmaf(En, t1, t1);         // (En+1)*(Ez+1)
    return (p + q2) * __builtin_amdgcn_rcpf(dn);
}

// h ring slot: B-frag order. flat short idx = kt*512 + l*8 + i holds
// h[k][m=l&15]. Slot = 4 KiB; 8 slots = 32 KiB.
//
// SCAN STRUCTURE IS FINAL (R7/R9/R10 post-mortems): 8 WGs x 512 thr,
// 16 batches/WG. Per-CU VALU gate work (~800 cy/SIMD/step) is pinned: the
// j-dim can't split across CUs (per-step h exchange), batch lives on the
// lane axis (splitting it doesn't reduce per-thread work), wave duplication
// regresses (R7), fusing more MFMA regresses (R9).

// ---------------------------------------------------------------------------
// Layer 0 scan (in-scan x-path): gates = Whh.h + Wih.x. 8 WGs x 512 thr.
// ---------------------------------------------------------------------------
__global__ __launch_bounds__(512) void gru_l0_mfma(
    const float* __restrict__ x,
    const float* __restrict__ wih_f, const float* __restrict__ whh_f,
    const float* __restrict__ bih_f, const float* __restrict__ bhh_f,
    const float* __restrict__ wih_r, const float* __restrict__ whh_r,
    const float* __restrict__ bih_r, const float* __restrict__ bhh_r,
    bf16* __restrict__ l0h)
{
    __shared__ __align__(16) bf16 hring[RING][2048];
    __shared__ __align__(16) bf16 xbuf[2][WIN][512];   // B-frag order

    const int bx   = blockIdx.x;
    const int dir  = bx >> 2;
    const int bg   = bx & 3;
    const int b0   = bg * 16;
    const int tid  = threadIdx.x;
    const int lane = tid & 63;
    const int wv   = tid >> 6;       // = jt (j-tile)
    const int col  = lane & 15;
    const int quad = lane >> 4;

    const float* Wih = dir ? wih_r : wih_f;
    const float* Whh = dir ? whh_r : whh_f;
    const float* Bih = dir ? bih_r : bih_f;
    const float* Bhh = dir ? bhh_r : bhh_f;

    const float GSC[3] = {NEGL2E, NEGL2E, TWOL2E};

    s16x8 wfr[3][4], wxf[3];
    #pragma unroll
    for (int g = 0; g < 3; ++g) {
        const float sc = GSC[g];
        const float* wrow = Whh + (size_t)(g * H_ + wv * 16 + col) * H_;
        #pragma unroll
        for (int kt = 0; kt < 4; ++kt) {
            const float* p = wrow + kt * 32 + quad * 8;
            s16x8 f;
            #pragma unroll
            for (int i = 0; i < 8; ++i) f[i] = f2bs(p[i] * sc);
            wfr[g][kt] = f;
        }
        const float* xrow = Wih + (size_t)(g * H_ + wv * 16 + col) * D0_;
        s16x8 fx;
        #pragma unroll
        for (int i = 0; i < 8; ++i) {
            const int k = quad * 8 + i;
            fx[i] = (k < D0_) ? f2bs(xrow[k] * sc) : (short)0;
        }
        wxf[g] = fx;
    }
    // per-r seeds: j = wv*16 + quad*4 + r (pre-scaled)
    f32x4 sR, sZ, sX, sN;
    #pragma unroll
    for (int r = 0; r < 4; ++r) {
        const int j = wv * 16 + quad * 4 + r;
        sR[r] = (Bih[j]        + Bhh[j])      * NEGL2E;
        sZ[r] = (Bih[H_ + j]   + Bhh[H_ + j]) * NEGL2E;
        sX[r] = Bih[2*H_ + j]  * TWOL2E;
        sN[r] = Bhh[2*H_ + j]  * TWOL2E;
    }

    // h' write slot (B-frag position for j = wv*16+quad*4+r, m = col)
    const int wkt   = wv >> 1;
    const int wl    = (((wv << 1) + (quad >> 1)) & 3) * 16 + col;
    const int woff  = wkt * 512 + wl * 8 + (quad & 1) * 4;   // shorts

    for (int i = tid; i < 2048; i += 512) hring[0][i] = __float2bfloat16(0.0f);
    // stage x window 0 (B-frag order)
    #pragma unroll
    for (int k = 0; k < 4; ++k) {
        const int i = tid + k * 512;
        const int si = i >> 9, rem = i & 511;
        const int m = (rem >> 5) & 15, c = rem & 31;
        const int t = dir ? (T_ - 1 - si) : si;
        const float v = (c < D0_) ? x[((size_t)(b0 + m) * T_ + t) * D0_ + c] : 0.0f;
        xbuf[0][si][((c >> 3) * 16 + m) * 8 + (c & 7)] = __float2bfloat16(v);
    }
    __syncthreads();

    float hprev[4] = {0.f, 0.f, 0.f, 0.f};
    float xv[4];

    for (int w = 0; w < NW; ++w) {
        const int par = w & 1;
        s16x8 axf[WIN];
        #pragma unroll
        for (int si = 0; si < WIN; ++si)
            axf[si] = *(const s16x8*)&xbuf[par][si][lane * 8];

        #pragma unroll
        for (int si = 0; si < WIN; ++si) {
            const int s  = w * WIN + si;
            const int rb = s & (RING - 1);
            const int wb = (s + 1) & (RING - 1);

            s16x8 hfr[4];
            #pragma unroll
            for (int kt = 0; kt < 4; ++kt)
                hfr[kt] = *(const s16x8*)&hring[rb][kt * 512 + lane * 8];

            f32x4 aR = MFMA16(wxf[0], axf[si], sR);
            f32x4 aZ = MFMA16(wxf[1], axf[si], sZ);
            f32x4 aX = MFMA16(wxf[2], axf[si], sX);
            f32x4 aN = sN;
            #pragma unroll
            for (int kt = 0; kt < 4; ++kt) {
                aR = MFMA16(wfr[0][kt], hfr[kt], aR);
                aZ = MFMA16(wfr[1][kt], hfr[kt], aZ);
                aN = MFMA16(wfr[2][kt], hfr[kt], aN);
            }

            // flush of previous window, in the MFMA/ds_read shadow.
            if (si == 1 && w > 0) {
                #pragma unroll
                for (int k = 0; k < 2; ++k) {
                    const int c  = tid + k * 512;
                    const int dt = c >> 8, m = (c >> 4) & 15, jo = c & 15;
                    const int fs = (w - 1) * WIN + dt;
                    const int t  = dir ? (T_ - 1 - fs) : fs;
                    const uint4 v = *(const uint4*)
                        &hring[(fs + 1) & (RING - 1)][(jo >> 2) * 512 + ((jo & 3) * 16 + m) * 8];
                    *(uint4*)(l0h + ((size_t)(b0 + m) * T_ + t) * 256 + dir * H_ + jo * 8) = v;
                }
            }

            // prefetch next window's x in the MFMA shadow
            if (si == 0 && w + 1 < NW) {
                #pragma unroll
                for (int k = 0; k < 4; ++k) {
                    const int i = tid + k * 512;
                    const int sj = i >> 9, rem = i & 511;
                    const int m = (rem >> 5) & 15, c = rem & 31;
                    const int s2 = (w + 1) * WIN + sj;
                    const int t2 = dir ? (T_ - 1 - s2) : s2;
                    xv[k] = (c < D0_) ? x[((size_t)(b0 + m) * T_ + t2) * D0_ + c] : 0.0f;
                }
            }

            float hn4[4];
            #pragma unroll
            for (int r = 0; r < 4; ++r) {
                const float hn = gru_update(aR[r], aZ[r], aN[r], aX[r], hprev[r]);
                hprev[r] = hn;
                hn4[r] = hn;
            }
            *(uint2*)&hring[wb][woff] = pk_bf16x4(hn4[0], hn4[1], hn4[2], hn4[3]);

            if (si == 3 && w + 1 < NW) {
                #pragma unroll
                for (int k = 0; k < 4; ++k) {
                    const int i = tid + k * 512;
                    const int sj = i >> 9, rem = i & 511;
                    const int m = (rem >> 5) & 15, c = rem & 31;
                    xbuf[par ^ 1][sj][((c >> 3) * 16 + m) * 8 + (c & 7)] =
                        __float2bfloat16(xv[k]);
                }
            }
            step_sync();
        }
    }
    // tail flush: window NW-1
    #pragma unroll
    for (int k = 0; k < 2; ++k) {
        const int c  = tid + k * 512;
        const int dt = c >> 8, m = (c >> 4) & 15, jo = c & 15;
        const int fs = (NW - 1) * WIN + dt;
        const int t  = dir ? (T_ - 1 - fs) : fs;
        const uint4 v = *(const uint4*)
            &hring[(fs + 1) & (RING - 1)][(jo >> 2) * 512 + ((jo & 3) * 16 + m) * 8];
        *(uint4*)(l0h + ((size_t)(b0 + m) * T_ + t) * 256 + dir * H_ + jo * 8) = v;
    }
}

// ---------------------------------------------------------------------------
// xg GEMM for layer-1 inputs (R11): gate loop INSIDE the block with the full
// A-tile resident in LDS. A (l0h) staged ONCE per (bg, t-octet, dir) instead
// of 3x (per-gate blocks) -> A traffic 384 MB -> 128 MB. W conversion via
// v_cvt_pk_bf16_f32 (halves cvt VALU). Store mapping identical to R6
// (64 consecutive uint2 = 512 B per instr). blockIdx.x = bg*256 + t-octet;
// .z = dir.
// ---------------------------------------------------------------------------
__global__ __launch_bounds__(256, 2) void xg_gemm_mfma(
    const bf16* __restrict__ A,
    const float* __restrict__ w_f, const float* __restrict__ w_r,
    const float* __restrict__ bi_f, const float* __restrict__ bi_r,
    const float* __restrict__ bh_f, const float* __restrict__ bh_r,
    bf16* __restrict__ xg_f, bf16* __restrict__ xg_r)
{
    __shared__ short As[128 * 264];   // 66 KB: full A tile (128 bt x 256 k), pad 264
    __shared__ short Ws[128 * 40];    // 10 KB: per-k0 W tile
    __shared__ float Bias_s[128];

    const int dir  = blockIdx.z;
    const float* W   = dir ? w_r : w_f;
    const float* bi  = dir ? bi_r : bi_f;
    const float* bh  = dir ? bh_r : bh_f;
    bf16* xg         = dir ? xg_r : xg_f;

    const int tid  = threadIdx.x;
    const int lane = tid & 63;
    const int wv   = tid >> 6;
    const int col  = lane & 15;
    const int quad = lane >> 4;
    const int bx   = blockIdx.x;
    const int bg   = bx >> 8;                 // 16-batch group
    const int t0   = (bx & 255) * 8;          // t octet

    const f32x4 z4 = {0.f, 0.f, 0.f, 0.f};

    // stage full A tile once: row = dt*16 + m  ->  l0h[(bg*16+m)*T + t0+dt]
    #pragma unroll
    for (int i = 0; i < 16; ++i) {
        const int c = tid + i * 256;          // c in [0, 4096): 128 rows x 32 uint4
        const int row = c >> 5, q8 = c & 31;
        const int dt = row >> 4, m = row & 15;
        *(uint4*)&As[row * 264 + q8 * 8] =
            *(const uint4*)(A + ((size_t)(bg * 16 + m) * T_ + t0 + dt) * 256 + q8 * 8);
    }
    __syncthreads();

    for (int g = 0; g < 3; ++g) {
        const int m0 = g * 128;
        const float sc = (g < 2) ? NEGL2E : TWOL2E;

        if (tid < 128) {
            const int n = m0 + tid;
            Bias_s[tid] = (bi[n] + ((n < 2 * H_) ? bh[n] : 0.0f)) * sc;
        }

        f32x4 acc[2][8];
        #pragma unroll
        for (int mt = 0; mt < 2; ++mt)
            #pragma unroll
            for (int nt = 0; nt < 8; ++nt) acc[mt][nt] = z4;

        for (int k0 = 0; k0 < 256; k0 += 32) {
            // stage Ws for this (gate, k0): pk-converted bf16
            #pragma unroll
            for (int i = 0; i < 4; ++i) {
                const int c = tid + i * 256;
                const int row = c >> 3, q = c & 7;
                const float4 v = *(const float4*)(W + (size_t)(m0 + row) * 256 + k0 + q * 4);
                *(uint2*)&Ws[row * 40 + q * 4] =
                    pk_bf16x4(v.x * sc, v.y * sc, v.z * sc, v.w * sc);
            }
            __syncthreads();

            s16x8 wfr[2], hfr[8];
            #pragma unroll
            for (int mt = 0; mt < 2; ++mt)
                wfr[mt] = *(const s16x8*)&Ws[(wv * 32 + mt * 16 + col) * 40 + quad * 8];
            #pragma unroll
            for (int nt = 0; nt < 8; ++nt)
                hfr[nt] = *(const s16x8*)&As[(nt * 16 + col) * 264 + k0 + quad * 8];

            #pragma unroll
            for (int mt = 0; mt < 2; ++mt)
                #pragma unroll
                for (int nt = 0; nt < 8; ++nt)
                    acc[mt][nt] = MFMA16(wfr[mt], hfr[nt], acc[mt][nt]);
            __syncthreads();
        }

        // store: per (mt,nt) instr, 64 lanes write 64 consecutive uint2 = 512 B.
        #pragma unroll
        for (int mt = 0; mt < 2; ++mt) {
            const int jt = wv * 2 + mt;
            float bv[4];
            #pragma unroll
            for (int r = 0; r < 4; ++r)
                bv[r] = Bias_s[wv * 32 + mt * 16 + quad * 4 + r];
            #pragma unroll
            for (int nt = 0; nt < 8; ++nt) {
                const uint2 o = pk_bf16x4(acc[mt][nt][0] + bv[0],
                                          acc[mt][nt][1] + bv[1],
                                          acc[mt][nt][2] + bv[2],
                                          acc[mt][nt][3] + bv[3]);
                const size_t idx = ((((size_t)bg * T_ + t0 + nt) * 3 + g) * 8 + jt) * 64
                                 + quad * 16 + col;
                ((uint2*)xg)[idx] = o;
            }
        }
        __syncthreads();   // protect Bias_s/Ws before next gate overwrites
    }
}

// ---------------------------------------------------------------------------
// Layer 1 scan: seeds from xgC (3 coalesced uint2/step, window-prefetched).
// ---------------------------------------------------------------------------
__global__ __launch_bounds__(512) void gru_l1_mfma(
    const bf16* __restrict__ xg_f, const bf16* __restrict__ xg_r,
    const float* __restrict__ whh_f, const float* __restrict__ bhh_f,
    const float* __restrict__ whh_r, const float* __restrict__ bhh_r,
    bf16* __restrict__ l1h, int fixed_dir)
{
    __shared__ __align__(16) bf16 hring[RING][2048];

    const int bx   = blockIdx.x;
    const int dir  = (fixed_dir >= 0) ? fixed_dir : (bx >> 2);
    const int bg   = bx & 3;
    const int b0   = bg * 16;
    const int tid  = threadIdx.x;
    const int lane = tid & 63;
    const int wv   = tid >> 6;
    const int col  = lane & 15;
    const int quad = lane >> 4;

    const bf16*  XG  = dir ? xg_r : xg_f;
    const float* Whh = dir ? whh_r : whh_f;
    const float* Bhh = dir ? bhh_r : bhh_f;

    const float GSC[3] = {NEGL2E, NEGL2E, TWOL2E};

    s16x8 wfr[3][4];
    #pragma unroll
    for (int g = 0; g < 3; ++g) {
        const float sc = GSC[g];
        const float* wrow = Whh + (size_t)(g * H_ + wv * 16 + col) * H_;
        #pragma unroll
        for (int kt = 0; kt < 4; ++kt) {
            const float* p = wrow + kt * 32 + quad * 8;
            s16x8 f;
            #pragma unroll
            for (int i = 0; i < 8; ++i) f[i] = f2bs(p[i] * sc);
            wfr[g][kt] = f;
        }
    }
    f32x4 sN;
    #pragma unroll
    for (int r = 0; r < 4; ++r)
        sN[r] = Bhh[2*H_ + wv * 16 + quad * 4 + r] * TWOL2E;

    const int wkt  = wv >> 1;
    const int wl   = (((wv << 1) + (quad >> 1)) & 3) * 16 + col;
    const int woff = wkt * 512 + wl * 8 + (quad & 1) * 4;

    for (int i = tid; i < 2048; i += 512) hring[0][i] = __float2bfloat16(0.0f);

    // xgC base: [bg][t][g][jt][lane] uint2
    const uint2* xgb = (const uint2*)XG + ((size_t)bg * T_) * 3 * 8 * 64;
    const int lidx = wv * 64 + lane;   // jt*64 + lane

    uint2 xcur[WIN][3], xnxt[WIN][3];
    #pragma unroll
    for (int si = 0; si < WIN; ++si) {
        const int t = dir ? (T_ - 1 - si) : si;
        #pragma unroll
        for (int g = 0; g < 3; ++g)
            xcur[si][g] = xgb[((size_t)t * 3 + g) * 512 + lidx];
    }
    __syncthreads();

    float hprev[4] = {0.f, 0.f, 0.f, 0.f};

    for (int w = 0; w < NW; ++w) {
        #pragma unroll
        for (int si = 0; si < WIN; ++si) {
            const int s  = w * WIN + si;
            const int rb = s & (RING - 1);
            const int wb = (s + 1) & (RING - 1);

            s16x8 hfr[4];
            #pragma unroll
            for (int kt = 0; kt < 4; ++kt)
                hfr[kt] = *(const s16x8*)&hring[rb][kt * 512 + lane * 8];

            // unpack seeds while ds_reads are in flight (values pre-scaled)
            const uint2 xr2 = xcur[si][0], xz2 = xcur[si][1], xn2 = xcur[si][2];
            const f32x4 seedR = (f32x4){
                __uint_as_float(xr2.x << 16), __uint_as_float(xr2.x & 0xffff0000u),
                __uint_as_float(xr2.y << 16), __uint_as_float(xr2.y & 0xffff0000u)};
            const f32x4 seedZ = (f32x4){
                __uint_as_float(xz2.x << 16), __uint_as_float(xz2.x & 0xffff0000u),
                __uint_as_float(xz2.y << 16), __uint_as_float(xz2.y & 0xffff0000u)};
            const float xnf[4] = {
                __uint_as_float(xn2.x << 16), __uint_as_float(xn2.x & 0xffff0000u),
                __uint_as_float(xn2.y << 16), __uint_as_float(xn2.y & 0xffff0000u)};

            // single chained accumulator per gate
            f32x4 aR = seedR, aZ = seedZ, aN = sN;
            #pragma unroll
            for (int kt = 0; kt < 4; ++kt) {
                aR = MFMA16(wfr[0][kt], hfr[kt], aR);
                aZ = MFMA16(wfr[1][kt], hfr[kt], aZ);
                aN = MFMA16(wfr[2][kt], hfr[kt], aN);
            }

            // flush of previous window, in the MFMA/ds_read shadow
            if (si == 1 && w > 0) {
                #pragma unroll
                for (int k = 0; k < 2; ++k) {
                    const int c  = tid + k * 512;
                    const int dt = c >> 8, m = (c >> 4) & 15, jo = c & 15;
                    const int fs = (w - 1) * WIN + dt;
                    const int t  = dir ? (T_ - 1 - fs) : fs;
                    const uint4 v = *(const uint4*)
                        &hring[(fs + 1) & (RING - 1)][(jo >> 2) * 512 + ((jo & 3) * 16 + m) * 8];
                    *(uint4*)(l1h + ((size_t)(b0 + m) * T_ + t) * 256 + dir * H_ + jo * 8) = v;
                }
            }

            if (si == 0 && w + 1 < NW) {
                #pragma unroll
                for (int sj = 0; sj < WIN; ++sj) {
                    const int s2 = (w + 1) * WIN + sj;
                    const int t2 = dir ? (T_ - 1 - s2) : s2;
                    #pragma unroll
                    for (int g = 0; g < 3; ++g)
                        xnxt[sj][g] = xgb[((size_t)t2 * 3 + g) * 512 + lidx];
                }
            }

            float hn4[4];
            #pragma unroll
            for (int r = 0; r < 4; ++r) {
                const float hn = gru_update(aR[r], aZ[r], aN[r], xnf[r], hprev[r]);
                hprev[r] = hn;
                hn4[r] = hn;
            }
            *(uint2*)&hring[wb][woff] = pk_bf16x4(hn4[0], hn4[1], hn4[2], hn4[3]);

            step_sync();
        }

        #pragma unroll
        for (int si = 0; si < WIN; ++si) {
            xcur[si][0] = xnxt[si][0];
            xcur[si][1] = xnxt[si][1];
            xcur[si][2] = xnxt[si][2];
        }
    }
    // tail flush: window NW-1
    #pragma unroll
    for (int k = 0; k < 2; ++k) {
        const int c  = tid + k * 512;
        const int dt = c >> 8, m = (c >> 4) & 15, jo = c & 15;
        const int fs = (NW - 1) * WIN + dt;
        const int t  = dir ? (T_ - 1 - fs) : fs;
        const uint4 v = *(const uint4*)
            &hring[(fs + 1) & (RING - 1)][(jo >> 2) * 512 + ((jo & 3) * 16 + m) * 8];
        *(uint4*)(l1h + ((size_t)(b0 + m) * T_ + t) * 256 + dir * H_ + jo * 8) = v;
    }
}

// ---------------------------------------------------------------------------
// FC epilogue: out[bt][c] = fc_b[c] + fc_w[c][:] . l1h[bt][:]
// ---------------------------------------------------------------------------
__global__ __launch_bounds__(256, 2) void fc_kernel(
    const bf16* __restrict__ h, const float* __restrict__ fcw,
    const float* __restrict__ fcb, float* __restrict__ out)
{
    __shared__ float w0[256], w1[256];
    const int tid = threadIdx.x;
    w0[tid] = fcw[tid];
    w1[tid] = fcw[256 + tid];
    __syncthreads();

    const size_t bt = (size_t)blockIdx.x * 256 + tid;
    const bf16* hp = h + bt * 256;
    float s0 = fcb[0], s1 = fcb[1];
    #pragma unroll 4
    for (int k8 = 0; k8 < 32; ++k8) {
        const uint4 u = *(const uint4*)(hp + k8 * 8);
        const unsigned uu[4] = {u.x, u.y, u.z, u.w};
        #pragma unroll
        for (int p = 0; p < 4; ++p) {
            const float v0 = __uint_as_float(uu[p] << 16);
            const float v1 = __uint_as_float(uu[p] & 0xffff0000u);
            const int k = k8 * 8 + p * 2;
            s0 = fmaf(w0[k], v0, s0);     s1 = fmaf(w1[k], v0, s1);
            s0 = fmaf(w0[k + 1], v1, s0); s1 = fmaf(w1[k + 1], v1, s1);
        }
    }
    out[bt * 2]     = s0;
    out[bt * 2 + 1] = s1;
}

extern "C" void kernel_launch(void* const* d_in, const int* in_sizes, int n_in,
                              void* d_out, int out_size, void* d_ws, size_t ws_size,
                              hipStream_t stream)
{
    if (n_in < 19) return;
    const float* x     = (const float*)d_in[0];
    const float* wih0  = (const float*)d_in[1];
    const float* whh0  = (const float*)d_in[2];
    const float* bih0  = (const float*)d_in[3];
    const float* bhh0  = (const float*)d_in[4];
    const float* wih0r = (const float*)d_in[5];
    const float* whh0r = (const float*)d_in[6];
    const float* bih0r = (const float*)d_in[7];
    const float* bhh0r = (const float*)d_in[8];
    const float* wih1  = (const float*)d_in[9];
    const float* whh1  = (const float*)d_in[10];
    const float* bih1  = (const float*)d_in[11];
    const float* bhh1  = (const float*)d_in[12];
    const float* wih1r = (const float*)d_in[13];
    const float* whh1r = (const float*)d_in[14];
    const float* bih1r = (const float*)d_in[15];
    const float* bhh1r = (const float*)d_in[16];
    const float* fcw   = (const float*)d_in[17];
    const float* fcb   = (const float*)d_in[18];
    float* out = (float*)d_out;

    const size_t nBT  = (size_t)B_ * T_;
    const size_t hh_b = nBT * 2 * H_ * sizeof(bf16);     // 64 MiB
    const size_t xg_b = nBT * G_ * sizeof(bf16);         // 96 MiB per dir
    const size_t xg_el = nBT * G_;

    if (ws_size >= hh_b + 2 * xg_b) {                    // 256 MiB path
        bf16* l0h = (bf16*)d_ws;
        bf16* xgf = (bf16*)((char*)d_ws + hh_b);
        bf16* xgr = xgf + xg_el;

        gru_l0_mfma<<<dim3(8), dim3(512), 0, stream>>>(
            x, wih0, whh0, bih0, bhh0, wih0r, whh0r, bih0r, bhh0r, l0h);
        xg_gemm_mfma<<<dim3(1024, 1, 2), dim3(256), 0, stream>>>(
            l0h, wih1, wih1r, bih1, bih1r, bhh1, bhh1r, xgf, xgr);
        gru_l1_mfma<<<dim3(8), dim3(512), 0, stream>>>(
            xgf, xgr, whh1, bhh1, whh1r, bhh1r, l0h, -1);   // l1h aliases l0h
        fc_kernel<<<dim3((int)(nBT / 256)), dim3(256), 0, stream>>>(l0h, fcw, fcb, out);
    } else if (ws_size >= 2 * hh_b + xg_b) {             // 224 MiB sequential
        bf16* l0h = (bf16*)d_ws;
        bf16* xg  = (bf16*)((char*)d_ws + hh_b);
        bf16* l1h = (bf16*)((char*)d_ws + hh_b + xg_b);

        gru_l0_mfma<<<dim3(8), dim3(512), 0, stream>>>(
            x, wih0, whh0, bih0, bhh0, wih0r, whh0r, bih0r, bhh0r, l0h);
        xg_gemm_mfma<<<dim3(1024, 1, 1), dim3(256), 0, stream>>>(
            l0h, wih1, wih1, bih1, bih1, bhh1, bhh1, xg, xg);
        gru_l1_mfma<<<dim3(4), dim3(512), 0, stream>>>(
            xg, xg, whh1, bhh1, whh1r, bhh1r, l1h, 0);
        xg_gemm_mfma<<<dim3(1024, 1, 1), dim3(256), 0, stream>>>(
            l0h, wih1r, wih1r, bih1r, bih1r, bhh1r, bhh1r, xg, xg);
        gru_l1_mfma<<<dim3(4), dim3(512), 0, stream>>>(
            xg, xg, whh1, bhh1, whh1r, bhh1r, l1h, 1);
        fc_kernel<<<dim3((int)(nBT / 256)), dim3(256), 0, stream>>>(l1h, fcw, fcb, out);
    }
}

// Round 12
// 2502.330 us; speedup vs baseline: 1.0293x; 1.0293x over previous
//
#include <hip/hip_runtime.h>
#include <hip/hip_bf16.h>

#define B_   64
#define T_   2048
#define H_   128
#define G_   384      // 3*H
#define D0_  18
#define WIN  4
#define RING 8
#define NW   (T_ / WIN)   // 512

typedef __hip_bfloat16 bf16;
typedef __attribute__((ext_vector_type(4))) float f32x4;
typedef __attribute__((ext_vector_type(8))) short s16x8;

#define LOG2E  1.4426950408889634f
#define NEGL2E (-1.4426950408889634f)
#define TWOL2E (2.8853900817779268f)

// Exp2-domain gate math (weights pre-scaled: R,Z by -LOG2E; N by +2*LOG2E):
//   h' = n + z*(h-n) = [Ez*(En-1) + h*(En+1)] / [(En+1)*(1+Ez)]
__device__ __forceinline__ short f2bs(float v) {
    bf16 b = __float2bfloat16(v);
    return *reinterpret_cast<short*>(&b);
}
__device__ __forceinline__ unsigned short f2bu(float v) {
    bf16 b = __float2bfloat16(v);
    return *reinterpret_cast<unsigned short*>(&b);
}
// Pack 4 f32 -> uint2 of 4 bf16 (RNE) in 2 instrs.
__device__ __forceinline__ uint2 pk_bf16x4(float a, float b, float c, float d) {
    uint2 r;
    asm("v_cvt_pk_bf16_f32 %0, %1, %2" : "=v"(r.x) : "v"(a), "v"(b));
    asm("v_cvt_pk_bf16_f32 %0, %1, %2" : "=v"(r.y) : "v"(c), "v"(d));
    return r;
}
#define MFMA16(A, B, C) __builtin_amdgcn_mfma_f32_16x16x32_bf16((A), (B), (C), 0, 0, 0)

// Per-step sync: hardware barrier; vmcnt NOT drained (prefetch stays in flight).
__device__ __forceinline__ void step_sync() {
    __asm__ volatile("s_waitcnt lgkmcnt(0)" ::: "memory");
    __builtin_amdgcn_s_barrier();
    __asm__ volatile("" ::: "memory");
}

// Combined GRU update from exp2-domain accumulators. 8 regular + 5 trans ops.
__device__ __forceinline__ float gru_update(float yr, float yz, float aN,
                                            float aX, float h) {
    const float Er = __builtin_amdgcn_exp2f(yr);
    const float rg = __builtin_amdgcn_rcpf(1.0f + Er);
    const float En = __builtin_amdgcn_exp2f(fmaf(rg, aN, aX));
    const float Ez = __builtin_amdgcn_exp2f(yz);
    const float p  = fmaf(En, Ez, -Ez);        // Ez*(En-1), fma-exact
    const float q2 = fmaf(h, En, h);           // h*(En+1)
    const float t1 = Ez + 1.0f;
    const float dn = fmaf(En, t1, t1);         // (En+1)*(Ez+1)
    return (p + q2) * __builtin_amdgcn_rcpf(dn);
}

// h ring slot: B-frag order. flat short idx = kt*512 + l*8 + i holds
// h[k][m=l&15]. Slot = 4 KiB; 8 slots = 32 KiB.
//
// FINAL STRUCTURE (measured across R6-R11):
//  - Scans: 8 WGs x 512 thr, 16 batches/WG. Per-CU VALU gate work is the
//    floor (~800 cy/SIMD/step). Refuted alternatives: wave-duplication
//    (R7, 2x regression), x-path fusion into l1 (R9, 1.6x regression),
//    batch-split (R10, neutral: batch is on the lane axis).
//  - xg: per-gate blocks + coalesced 512B stores (R6). A-resident (R11)
//    and dir-hoist (R8) variants measured neutral.

// ---------------------------------------------------------------------------
// Layer 0 scan (in-scan x-path): gates = Whh.h + Wih.x. 8 WGs x 512 thr.
// ---------------------------------------------------------------------------
__global__ __launch_bounds__(512) void gru_l0_mfma(
    const float* __restrict__ x,
    const float* __restrict__ wih_f, const float* __restrict__ whh_f,
    const float* __restrict__ bih_f, const float* __restrict__ bhh_f,
    const float* __restrict__ wih_r, const float* __restrict__ whh_r,
    const float* __restrict__ bih_r, const float* __restrict__ bhh_r,
    bf16* __restrict__ l0h)
{
    __shared__ __align__(16) bf16 hring[RING][2048];
    __shared__ __align__(16) bf16 xbuf[2][WIN][512];   // B-frag order

    const int bx   = blockIdx.x;
    const int dir  = bx >> 2;
    const int bg   = bx & 3;
    const int b0   = bg * 16;
    const int tid  = threadIdx.x;
    const int lane = tid & 63;
    const int wv   = tid >> 6;       // = jt (j-tile)
    const int col  = lane & 15;
    const int quad = lane >> 4;

    const float* Wih = dir ? wih_r : wih_f;
    const float* Whh = dir ? whh_r : whh_f;
    const float* Bih = dir ? bih_r : bih_f;
    const float* Bhh = dir ? bhh_r : bhh_f;

    const float GSC[3] = {NEGL2E, NEGL2E, TWOL2E};

    s16x8 wfr[3][4], wxf[3];
    #pragma unroll
    for (int g = 0; g < 3; ++g) {
        const float sc = GSC[g];
        const float* wrow = Whh + (size_t)(g * H_ + wv * 16 + col) * H_;
        #pragma unroll
        for (int kt = 0; kt < 4; ++kt) {
            const float* p = wrow + kt * 32 + quad * 8;
            s16x8 f;
            #pragma unroll
            for (int i = 0; i < 8; ++i) f[i] = f2bs(p[i] * sc);
            wfr[g][kt] = f;
        }
        const float* xrow = Wih + (size_t)(g * H_ + wv * 16 + col) * D0_;
        s16x8 fx;
        #pragma unroll
        for (int i = 0; i < 8; ++i) {
            const int k = quad * 8 + i;
            fx[i] = (k < D0_) ? f2bs(xrow[k] * sc) : (short)0;
        }
        wxf[g] = fx;
    }
    // per-r seeds: j = wv*16 + quad*4 + r (pre-scaled)
    f32x4 sR, sZ, sX, sN;
    #pragma unroll
    for (int r = 0; r < 4; ++r) {
        const int j = wv * 16 + quad * 4 + r;
        sR[r] = (Bih[j]        + Bhh[j])      * NEGL2E;
        sZ[r] = (Bih[H_ + j]   + Bhh[H_ + j]) * NEGL2E;
        sX[r] = Bih[2*H_ + j]  * TWOL2E;
        sN[r] = Bhh[2*H_ + j]  * TWOL2E;
    }

    // h' write slot (B-frag position for j = wv*16+quad*4+r, m = col)
    const int wkt   = wv >> 1;
    const int wl    = (((wv << 1) + (quad >> 1)) & 3) * 16 + col;
    const int woff  = wkt * 512 + wl * 8 + (quad & 1) * 4;   // shorts

    for (int i = tid; i < 2048; i += 512) hring[0][i] = __float2bfloat16(0.0f);
    // stage x window 0 (B-frag order)
    #pragma unroll
    for (int k = 0; k < 4; ++k) {
        const int i = tid + k * 512;
        const int si = i >> 9, rem = i & 511;
        const int m = (rem >> 5) & 15, c = rem & 31;
        const int t = dir ? (T_ - 1 - si) : si;
        const float v = (c < D0_) ? x[((size_t)(b0 + m) * T_ + t) * D0_ + c] : 0.0f;
        xbuf[0][si][((c >> 3) * 16 + m) * 8 + (c & 7)] = __float2bfloat16(v);
    }
    __syncthreads();

    float hprev[4] = {0.f, 0.f, 0.f, 0.f};
    float xv[4];

    for (int w = 0; w < NW; ++w) {
        const int par = w & 1;
        s16x8 axf[WIN];
        #pragma unroll
        for (int si = 0; si < WIN; ++si)
            axf[si] = *(const s16x8*)&xbuf[par][si][lane * 8];

        #pragma unroll
        for (int si = 0; si < WIN; ++si) {
            const int s  = w * WIN + si;
            const int rb = s & (RING - 1);
            const int wb = (s + 1) & (RING - 1);

            s16x8 hfr[4];
            #pragma unroll
            for (int kt = 0; kt < 4; ++kt)
                hfr[kt] = *(const s16x8*)&hring[rb][kt * 512 + lane * 8];

            // x-MFMAs first (operands in regs, fill ds_read latency);
            // single chained accumulator per gate (no final adds).
            f32x4 aR = MFMA16(wxf[0], axf[si], sR);
            f32x4 aZ = MFMA16(wxf[1], axf[si], sZ);
            f32x4 aX = MFMA16(wxf[2], axf[si], sX);
            f32x4 aN = sN;
            #pragma unroll
            for (int kt = 0; kt < 4; ++kt) {
                aR = MFMA16(wfr[0][kt], hfr[kt], aR);
                aZ = MFMA16(wfr[1][kt], hfr[kt], aZ);
                aN = MFMA16(wfr[2][kt], hfr[kt], aN);
            }

            // flush of previous window, in the MFMA/ds_read shadow.
            // Slot safety: flush set {(w-1)*4+1 .. (w-1)*4+4} mod 8 is
            // disjoint from window-w writes {w*4+1 .. w*4+4} mod 8.
            if (si == 1 && w > 0) {
                #pragma unroll
                for (int k = 0; k < 2; ++k) {
                    const int c  = tid + k * 512;
                    const int dt = c >> 8, m = (c >> 4) & 15, jo = c & 15;
                    const int fs = (w - 1) * WIN + dt;
                    const int t  = dir ? (T_ - 1 - fs) : fs;
                    const uint4 v = *(const uint4*)
                        &hring[(fs + 1) & (RING - 1)][(jo >> 2) * 512 + ((jo & 3) * 16 + m) * 8];
                    *(uint4*)(l0h + ((size_t)(b0 + m) * T_ + t) * 256 + dir * H_ + jo * 8) = v;
                }
            }

            // prefetch next window's x in the MFMA shadow
            if (si == 0 && w + 1 < NW) {
                #pragma unroll
                for (int k = 0; k < 4; ++k) {
                    const int i = tid + k * 512;
                    const int sj = i >> 9, rem = i & 511;
                    const int m = (rem >> 5) & 15, c = rem & 31;
                    const int s2 = (w + 1) * WIN + sj;
                    const int t2 = dir ? (T_ - 1 - s2) : s2;
                    xv[k] = (c < D0_) ? x[((size_t)(b0 + m) * T_ + t2) * D0_ + c] : 0.0f;
                }
            }

            float hn4[4];
            #pragma unroll
            for (int r = 0; r < 4; ++r) {
                const float hn = gru_update(aR[r], aZ[r], aN[r], aX[r], hprev[r]);
                hprev[r] = hn;
                hn4[r] = hn;
            }
            *(uint2*)&hring[wb][woff] = pk_bf16x4(hn4[0], hn4[1], hn4[2], hn4[3]);

            if (si == 3 && w + 1 < NW) {
                #pragma unroll
                for (int k = 0; k < 4; ++k) {
                    const int i = tid + k * 512;
                    const int sj = i >> 9, rem = i & 511;
                    const int m = (rem >> 5) & 15, c = rem & 31;
                    xbuf[par ^ 1][sj][((c >> 3) * 16 + m) * 8 + (c & 7)] =
                        __float2bfloat16(xv[k]);
                }
            }
            step_sync();
        }
    }
    // tail flush: window NW-1
    #pragma unroll
    for (int k = 0; k < 2; ++k) {
        const int c  = tid + k * 512;
        const int dt = c >> 8, m = (c >> 4) & 15, jo = c & 15;
        const int fs = (NW - 1) * WIN + dt;
        const int t  = dir ? (T_ - 1 - fs) : fs;
        const uint4 v = *(const uint4*)
            &hring[(fs + 1) & (RING - 1)][(jo >> 2) * 512 + ((jo & 3) * 16 + m) * 8];
        *(uint4*)(l0h + ((size_t)(b0 + m) * T_ + t) * 256 + dir * H_ + jo * 8) = v;
    }
}

// ---------------------------------------------------------------------------
// xg GEMM for layer-1 inputs (R6: coalesced-store n-tile mapping).
// Block = (bg: 16 batches) x (8 consecutive t): C-frag col = batch m, so
// each store instr writes 64 consecutive uint2 (512 B contiguous).
// blockIdx.x = bg*256 + t-octet; .y = gate; .z = dir.
// ---------------------------------------------------------------------------
__global__ __launch_bounds__(256, 2) void xg_gemm_mfma(
    const bf16* __restrict__ A,
    const float* __restrict__ w_f, const float* __restrict__ w_r,
    const float* __restrict__ bi_f, const float* __restrict__ bi_r,
    const float* __restrict__ bh_f, const float* __restrict__ bh_r,
    bf16* __restrict__ xg_f, bf16* __restrict__ xg_r)
{
    __shared__ short As[128 * 40];   // l0h rows: row = dt*16 + m
    __shared__ short Ws[128 * 40];   // W rows (j')
    __shared__ float Bias_s[128];

    const int dir  = blockIdx.z;
    const float* W   = dir ? w_r : w_f;
    const float* bi  = dir ? bi_r : bi_f;
    const float* bh  = dir ? bh_r : bh_f;
    bf16* xg         = dir ? xg_r : xg_f;

    const int tid  = threadIdx.x;
    const int lane = tid & 63;
    const int wv   = tid >> 6;
    const int col  = lane & 15;
    const int quad = lane >> 4;
    const int bx   = blockIdx.x;
    const int bg   = bx >> 8;                 // batch group (16 batches)
    const int t0   = (bx & 255) * 8;          // t octet
    const int g    = blockIdx.y;              // gate
    const int m0   = g * 128;

    const float sc = (g < 2) ? NEGL2E : TWOL2E;
    const f32x4 z4 = {0.f, 0.f, 0.f, 0.f};

    if (tid < 128) {
        const int n = m0 + tid;
        Bias_s[tid] = (bi[n] + ((n < 2 * H_) ? bh[n] : 0.0f)) * sc;
    }

    f32x4 acc[2][8];
    #pragma unroll
    for (int mt = 0; mt < 2; ++mt)
        #pragma unroll
        for (int nt = 0; nt < 8; ++nt) acc[mt][nt] = z4;

    for (int k0 = 0; k0 < 256; k0 += 32) {
        #pragma unroll
        for (int i = 0; i < 2; ++i) {
            const int c = tid + i * 256;
            const int row = c >> 2, q4 = c & 3;
            const int dt = row >> 4, m = row & 15;
            *(uint4*)&As[row * 40 + q4 * 8] =
                *(const uint4*)(A + (((size_t)(bg * 16 + m) * T_ + t0 + dt) * 256)
                                + k0 + q4 * 8);
        }
        #pragma unroll
        for (int i = 0; i < 4; ++i) {
            const int c = tid + i * 256;
            const int row = c >> 3, q = c & 7;
            const float4 v = *(const float4*)(W + (size_t)(m0 + row) * 256 + k0 + q * 4);
            ushort4 u;
            u.x = f2bu(v.x * sc); u.y = f2bu(v.y * sc);
            u.z = f2bu(v.z * sc); u.w = f2bu(v.w * sc);
            *(ushort4*)&Ws[row * 40 + q * 4] = u;
        }
        __syncthreads();

        s16x8 wfr[2], hfr[8];
        #pragma unroll
        for (int mt = 0; mt < 2; ++mt)
            wfr[mt] = *(const s16x8*)&Ws[(wv * 32 + mt * 16 + col) * 40 + quad * 8];
        #pragma unroll
        for (int nt = 0; nt < 8; ++nt)
            hfr[nt] = *(const s16x8*)&As[(nt * 16 + col) * 40 + quad * 8];

        #pragma unroll
        for (int mt = 0; mt < 2; ++mt)
            #pragma unroll
            for (int nt = 0; nt < 8; ++nt)
                acc[mt][nt] = MFMA16(wfr[mt], hfr[nt], acc[mt][nt]);
        __syncthreads();
    }

    // store: per (mt,nt) instr, 64 lanes write 64 consecutive uint2 = 512 B.
    #pragma unroll
    for (int mt = 0; mt < 2; ++mt) {
        const int jt = wv * 2 + mt;
        float bv[4];
        #pragma unroll
        for (int r = 0; r < 4; ++r)
            bv[r] = Bias_s[wv * 32 + mt * 16 + quad * 4 + r];
        #pragma unroll
        for (int nt = 0; nt < 8; ++nt) {
            const uint2 o = pk_bf16x4(acc[mt][nt][0] + bv[0],
                                      acc[mt][nt][1] + bv[1],
                                      acc[mt][nt][2] + bv[2],
                                      acc[mt][nt][3] + bv[3]);
            const size_t idx = ((((size_t)bg * T_ + t0 + nt) * 3 + g) * 8 + jt) * 64
                             + quad * 16 + col;
            ((uint2*)xg)[idx] = o;
        }
    }
}

// ---------------------------------------------------------------------------
// Layer 1 scan: seeds from xgC (3 coalesced uint2/step, window-prefetched).
// ---------------------------------------------------------------------------
__global__ __launch_bounds__(512) void gru_l1_mfma(
    const bf16* __restrict__ xg_f, const bf16* __restrict__ xg_r,
    const float* __restrict__ whh_f, const float* __restrict__ bhh_f,
    const float* __restrict__ whh_r, const float* __restrict__ bhh_r,
    bf16* __restrict__ l1h, int fixed_dir)
{
    __shared__ __align__(16) bf16 hring[RING][2048];

    const int bx   = blockIdx.x;
    const int dir  = (fixed_dir >= 0) ? fixed_dir : (bx >> 2);
    const int bg   = bx & 3;
    const int b0   = bg * 16;
    const int tid  = threadIdx.x;
    const int lane = tid & 63;
    const int wv   = tid >> 6;
    const int col  = lane & 15;
    const int quad = lane >> 4;

    const bf16*  XG  = dir ? xg_r : xg_f;
    const float* Whh = dir ? whh_r : whh_f;
    const float* Bhh = dir ? bhh_r : bhh_f;

    const float GSC[3] = {NEGL2E, NEGL2E, TWOL2E};

    s16x8 wfr[3][4];
    #pragma unroll
    for (int g = 0; g < 3; ++g) {
        const float sc = GSC[g];
        const float* wrow = Whh + (size_t)(g * H_ + wv * 16 + col) * H_;
        #pragma unroll
        for (int kt = 0; kt < 4; ++kt) {
            const float* p = wrow + kt * 32 + quad * 8;
            s16x8 f;
            #pragma unroll
            for (int i = 0; i < 8; ++i) f[i] = f2bs(p[i] * sc);
            wfr[g][kt] = f;
        }
    }
    f32x4 sN;
    #pragma unroll
    for (int r = 0; r < 4; ++r)
        sN[r] = Bhh[2*H_ + wv * 16 + quad * 4 + r] * TWOL2E;

    const int wkt  = wv >> 1;
    const int wl   = (((wv << 1) + (quad >> 1)) & 3) * 16 + col;
    const int woff = wkt * 512 + wl * 8 + (quad & 1) * 4;

    for (int i = tid; i < 2048; i += 512) hring[0][i] = __float2bfloat16(0.0f);

    // xgC base: [bg][t][g][jt][lane] uint2
    const uint2* xgb = (const uint2*)XG + ((size_t)bg * T_) * 3 * 8 * 64;
    const int lidx = wv * 64 + lane;   // jt*64 + lane

    uint2 xcur[WIN][3], xnxt[WIN][3];
    #pragma unroll
    for (int si = 0; si < WIN; ++si) {
        const int t = dir ? (T_ - 1 - si) : si;
        #pragma unroll
        for (int g = 0; g < 3; ++g)
            xcur[si][g] = xgb[((size_t)t * 3 + g) * 512 + lidx];
    }
    __syncthreads();

    float hprev[4] = {0.f, 0.f, 0.f, 0.f};

    for (int w = 0; w < NW; ++w) {
        #pragma unroll
        for (int si = 0; si < WIN; ++si) {
            const int s  = w * WIN + si;
            const int rb = s & (RING - 1);
            const int wb = (s + 1) & (RING - 1);

            s16x8 hfr[4];
            #pragma unroll
            for (int kt = 0; kt < 4; ++kt)
                hfr[kt] = *(const s16x8*)&hring[rb][kt * 512 + lane * 8];

            // unpack seeds while ds_reads are in flight (values pre-scaled)
            const uint2 xr2 = xcur[si][0], xz2 = xcur[si][1], xn2 = xcur[si][2];
            const f32x4 seedR = (f32x4){
                __uint_as_float(xr2.x << 16), __uint_as_float(xr2.x & 0xffff0000u),
                __uint_as_float(xr2.y << 16), __uint_as_float(xr2.y & 0xffff0000u)};
            const f32x4 seedZ = (f32x4){
                __uint_as_float(xz2.x << 16), __uint_as_float(xz2.x & 0xffff0000u),
                __uint_as_float(xz2.y << 16), __uint_as_float(xz2.y & 0xffff0000u)};
            const float xnf[4] = {
                __uint_as_float(xn2.x << 16), __uint_as_float(xn2.x & 0xffff0000u),
                __uint_as_float(xn2.y << 16), __uint_as_float(xn2.y & 0xffff0000u)};

            // single chained accumulator per gate
            f32x4 aR = seedR, aZ = seedZ, aN = sN;
            #pragma unroll
            for (int kt = 0; kt < 4; ++kt) {
                aR = MFMA16(wfr[0][kt], hfr[kt], aR);
                aZ = MFMA16(wfr[1][kt], hfr[kt], aZ);
                aN = MFMA16(wfr[2][kt], hfr[kt], aN);
            }

            // flush of previous window, in the MFMA/ds_read shadow
            if (si == 1 && w > 0) {
                #pragma unroll
                for (int k = 0; k < 2; ++k) {
                    const int c  = tid + k * 512;
                    const int dt = c >> 8, m = (c >> 4) & 15, jo = c & 15;
                    const int fs = (w - 1) * WIN + dt;
                    const int t  = dir ? (T_ - 1 - fs) : fs;
                    const uint4 v = *(const uint4*)
                        &hring[(fs + 1) & (RING - 1)][(jo >> 2) * 512 + ((jo & 3) * 16 + m) * 8];
                    *(uint4*)(l1h + ((size_t)(b0 + m) * T_ + t) * 256 + dir * H_ + jo * 8) = v;
                }
            }

            if (si == 0 && w + 1 < NW) {
                #pragma unroll
                for (int sj = 0; sj < WIN; ++sj) {
                    const int s2 = (w + 1) * WIN + sj;
                    const int t2 = dir ? (T_ - 1 - s2) : s2;
                    #pragma unroll
                    for (int g = 0; g < 3; ++g)
                        xnxt[sj][g] = xgb[((size_t)t2 * 3 + g) * 512 + lidx];
                }
            }

            float hn4[4];
            #pragma unroll
            for (int r = 0; r < 4; ++r) {
                const float hn = gru_update(aR[r], aZ[r], aN[r], xnf[r], hprev[r]);
                hprev[r] = hn;
                hn4[r] = hn;
            }
            *(uint2*)&hring[wb][woff] = pk_bf16x4(hn4[0], hn4[1], hn4[2], hn4[3]);

            step_sync();
        }

        #pragma unroll
        for (int si = 0; si < WIN; ++si) {
            xcur[si][0] = xnxt[si][0];
            xcur[si][1] = xnxt[si][1];
            xcur[si][2] = xnxt[si][2];
        }
    }
    // tail flush: window NW-1
    #pragma unroll
    for (int k = 0; k < 2; ++k) {
        const int c  = tid + k * 512;
        const int dt = c >> 8, m = (c >> 4) & 15, jo = c & 15;
        const int fs = (NW - 1) * WIN + dt;
        const int t  = dir ? (T_ - 1 - fs) : fs;
        const uint4 v = *(const uint4*)
            &hring[(fs + 1) & (RING - 1)][(jo >> 2) * 512 + ((jo & 3) * 16 + m) * 8];
        *(uint4*)(l1h + ((size_t)(b0 + m) * T_ + t) * 256 + dir * H_ + jo * 8) = v;
    }
}

// ---------------------------------------------------------------------------
// FC epilogue: out[bt][c] = fc_b[c] + fc_w[c][:] . l1h[bt][:]
// ---------------------------------------------------------------------------
__global__ __launch_bounds__(256, 2) void fc_kernel(
    const bf16* __restrict__ h, const float* __restrict__ fcw,
    const float* __restrict__ fcb, float* __restrict__ out)
{
    __shared__ float w0[256], w1[256];
    const int tid = threadIdx.x;
    w0[tid] = fcw[tid];
    w1[tid] = fcw[256 + tid];
    __syncthreads();

    const size_t bt = (size_t)blockIdx.x * 256 + tid;
    const bf16* hp = h + bt * 256;
    float s0 = fcb[0], s1 = fcb[1];
    #pragma unroll 4
    for (int k8 = 0; k8 < 32; ++k8) {
        const uint4 u = *(const uint4*)(hp + k8 * 8);
        const unsigned uu[4] = {u.x, u.y, u.z, u.w};
        #pragma unroll
        for (int p = 0; p < 4; ++p) {
            const float v0 = __uint_as_float(uu[p] << 16);
            const float v1 = __uint_as_float(uu[p] & 0xffff0000u);
            const int k = k8 * 8 + p * 2;
            s0 = fmaf(w0[k], v0, s0);     s1 = fmaf(w1[k], v0, s1);
            s0 = fmaf(w0[k + 1], v1, s0); s1 = fmaf(w1[k + 1], v1, s1);
        }
    }
    out[bt * 2]     = s0;
    out[bt * 2 + 1] = s1;
}

extern "C" void kernel_launch(void* const* d_in, const int* in_sizes, int n_in,
                              void* d_out, int out_size, void* d_ws, size_t ws_size,
                              hipStream_t stream)
{
    if (n_in < 19) return;
    const float* x     = (const float*)d_in[0];
    const float* wih0  = (const float*)d_in[1];
    const float* whh0  = (const float*)d_in[2];
    const float* bih0  = (const float*)d_in[3];
    const float* bhh0  = (const float*)d_in[4];
    const float* wih0r = (const float*)d_in[5];
    const float* whh0r = (const float*)d_in[6];
    const float* bih0r = (const float*)d_in[7];
    const float* bhh0r = (const float*)d_in[8];
    const float* wih1  = (const float*)d_in[9];
    const float* whh1  = (const float*)d_in[10];
    const float* bih1  = (const float*)d_in[11];
    const float* bhh1  = (const float*)d_in[12];
    const float* wih1r = (const float*)d_in[13];
    const float* whh1r = (const float*)d_in[14];
    const float* bih1r = (const float*)d_in[15];
    const float* bhh1r = (const float*)d_in[16];
    const float* fcw   = (const float*)d_in[17];
    const float* fcb   = (const float*)d_in[18];
    float* out = (float*)d_out;

    const size_t nBT  = (size_t)B_ * T_;
    const size_t hh_b = nBT * 2 * H_ * sizeof(bf16);     // 64 MiB
    const size_t xg_b = nBT * G_ * sizeof(bf16);         // 96 MiB per dir
    const size_t xg_el = nBT * G_;

    if (ws_size >= hh_b + 2 * xg_b) {                    // 256 MiB path
        bf16* l0h = (bf16*)d_ws;
        bf16* xgf = (bf16*)((char*)d_ws + hh_b);
        bf16* xgr = xgf + xg_el;

        gru_l0_mfma<<<dim3(8), dim3(512), 0, stream>>>(
            x, wih0, whh0, bih0, bhh0, wih0r, whh0r, bih0r, bhh0r, l0h);
        xg_gemm_mfma<<<dim3(1024, 3, 2), dim3(256), 0, stream>>>(
            l0h, wih1, wih1r, bih1, bih1r, bhh1, bhh1r, xgf, xgr);
        gru_l1_mfma<<<dim3(8), dim3(512), 0, stream>>>(
            xgf, xgr, whh1, bhh1, whh1r, bhh1r, l0h, -1);   // l1h aliases l0h
        fc_kernel<<<dim3((int)(nBT / 256)), dim3(256), 0, stream>>>(l0h, fcw, fcb, out);
    } else if (ws_size >= 2 * hh_b + xg_b) {             // 224 MiB sequential
        bf16* l0h = (bf16*)d_ws;
        bf16* xg  = (bf16*)((char*)d_ws + hh_b);
        bf16* l1h = (bf16*)((char*)d_ws + hh_b + xg_b);

        gru_l0_mfma<<<dim3(8), dim3(512), 0, stream>>>(
            x, wih0, whh0, bih0, bhh0, wih0r, whh0r, bih0r, bhh0r, l0h);
        xg_gemm_mfma<<<dim3(1024, 3, 1), dim3(256), 0, stream>>>(
            l0h, wih1, wih1, bih1, bih1, bhh1, bhh1, xg, xg);
        gru_l1_mfma<<<dim3(4), dim3(512), 0, stream>>>(
            xg, xg, whh1, bhh1, whh1r, bhh1r, l1h, 0);
        xg_gemm_mfma<<<dim3(1024, 3, 1), dim3(256), 0, stream>>>(
            l0h, wih1r, wih1r, bih1r, bih1r, bhh1r, bhh1r, xg, xg);
        gru_l1_mfma<<<dim3(4), dim3(512), 0, stream>>>(
            xg, xg, whh1, bhh1, whh1r, bhh1r, l1h, 1);
        fc_kernel<<<dim3((int)(nBT / 256)), dim3(256), 0, stream>>>(l1h, fcw, fcb, out);
    }
}